// Round 3
// baseline (703.299 us; speedup 1.0000x reference)
//
#include <hip/hip_runtime.h>

#define S_LEN 2048
#define D_MODEL 2048
#define NH 16
#define HD 128

typedef __attribute__((ext_vector_type(4))) float f32x4;
typedef __attribute__((ext_vector_type(8))) short short8;
typedef __attribute__((ext_vector_type(8))) __bf16 bf16x8;
typedef __attribute__((ext_vector_type(4))) unsigned short us4;

__device__ __forceinline__ unsigned short f2bf(float f) {
  unsigned int u = __builtin_bit_cast(unsigned int, f);
  return (unsigned short)((u + 0x7fffu + ((u >> 16) & 1u)) >> 16);
}

__device__ __forceinline__ f32x4 mfma_bf16(short8 a, short8 b, f32x4 c) {
  return __builtin_amdgcn_mfma_f32_16x16x32_bf16(
      __builtin_bit_cast(bf16x8, a), __builtin_bit_cast(bf16x8, b), c, 0, 0, 0);
}

__device__ __forceinline__ void gload16(const unsigned short* g, unsigned short* l) {
  __builtin_amdgcn_global_load_lds(
      (const __attribute__((address_space(1))) void*)g,
      (__attribute__((address_space(3))) void*)l, 16, 0, 0);
}

// ---------------- cast x (f32 -> bf16) ----------------
__global__ void cast_bf16(const float* __restrict__ src, unsigned short* __restrict__ dst, int n4) {
  int i = blockIdx.x * blockDim.x + threadIdx.x;
  if (i < n4) {
    float4 v = ((const float4*)src)[i];
    us4 o = { f2bf(v.x), f2bf(v.y), f2bf(v.z), f2bf(v.w) };
    ((us4*)dst)[i] = o;
  }
}

// ---------------- transpose-cast weights: W[k][n] f32 -> Wt[n][k] bf16 ----------------
__global__ void transpose_cast(const float* __restrict__ W, unsigned short* __restrict__ Wt) {
  __shared__ unsigned short tile[32][33];
  int bx = blockIdx.x * 32, by = blockIdx.y * 32;
  int tx = threadIdx.x, ty = threadIdx.y;
#pragma unroll
  for (int i = 0; i < 32; i += 8)
    tile[ty + i][tx] = f2bf(W[(by + ty + i) * D_MODEL + bx + tx]);
  __syncthreads();
#pragma unroll
  for (int i = 0; i < 32; i += 8)
    Wt[(bx + ty + i) * D_MODEL + by + tx] = tile[tx][ty + i];
}

// ---------------- GEMM: C[M,N] = A[M,K] @ Bt[N,K]^T, bf16 in, 128x128 tile ----------------
// MODE 0: bf16 row-major out. MODE 1: v-layout out [H][HD][S] (per-batch, M==S_LEN).
// MODE 2: f32 + bias out.
template <int MODE>
__global__ __launch_bounds__(256, 2) void gemm_bt(
    const unsigned short* __restrict__ A, const unsigned short* __restrict__ Bt,
    void* __restrict__ Cv, const float* __restrict__ bias, int Mdim, int Ndim, int Kdim) {
  __shared__ unsigned short lA[128 * 32];
  __shared__ unsigned short lB[128 * 32];
  const int t = threadIdx.x;
  const int l = t & 63, w = t >> 6;
  const int wr = w >> 1, wc = w & 1;
  const int lr = l & 15, lk = l >> 4;
  const int m0 = blockIdx.y * 128, n0 = blockIdx.x * 128;

  const int arow = t >> 2, acol = (t & 3) * 8;
  const unsigned short* Ag0 = A + (m0 + arow) * Kdim + acol;
  const unsigned short* Ag1 = Ag0 + 64 * Kdim;
  const unsigned short* Bg0 = Bt + (n0 + arow) * Kdim + acol;
  const unsigned short* Bg1 = Bg0 + 64 * Kdim;
  unsigned short* la = lA + t * 8;
  unsigned short* lb = lB + t * 8;

  f32x4 acc[4][4] = {};

  for (int kt = 0; kt < Kdim; kt += 32) {
    gload16(Ag0 + kt, la);
    gload16(Ag1 + kt, la + 2048);
    gload16(Bg0 + kt, lb);
    gload16(Bg1 + kt, lb + 2048);
    __syncthreads();
    short8 af[4], bf[4];
#pragma unroll
    for (int mi = 0; mi < 4; mi++)
      af[mi] = *(const short8*)&lA[(wr * 64 + mi * 16 + lr) * 32 + lk * 8];
#pragma unroll
    for (int ni = 0; ni < 4; ni++)
      bf[ni] = *(const short8*)&lB[(wc * 64 + ni * 16 + lr) * 32 + lk * 8];
#pragma unroll
    for (int mi = 0; mi < 4; mi++)
#pragma unroll
      for (int ni = 0; ni < 4; ni++)
        acc[mi][ni] = mfma_bf16(af[mi], bf[ni], acc[mi][ni]);
    __syncthreads();
  }

  if (MODE == 0) {
    unsigned short* C = (unsigned short*)Cv;
#pragma unroll
    for (int mi = 0; mi < 4; mi++) {
      int r0 = m0 + wr * 64 + mi * 16 + lk * 4;
#pragma unroll
      for (int ni = 0; ni < 4; ni++) {
        int c = n0 + wc * 64 + ni * 16 + lr;
#pragma unroll
        for (int r = 0; r < 4; r++)
          C[(r0 + r) * Ndim + c] = f2bf(acc[mi][ni][r]);
      }
    }
  } else if (MODE == 1) {
#pragma unroll
    for (int mi = 0; mi < 4; mi++) {
      int s = m0 + wr * 64 + mi * 16 + lk * 4;  // sequence position (4 consecutive)
#pragma unroll
      for (int ni = 0; ni < 4; ni++) {
        int n = n0 + wc * 64 + ni * 16 + lr;
        int h = n >> 7, d = n & (HD - 1);
        us4 pk = { f2bf(acc[mi][ni][0]), f2bf(acc[mi][ni][1]),
                   f2bf(acc[mi][ni][2]), f2bf(acc[mi][ni][3]) };
        *(us4*)&((unsigned short*)Cv)[(h * HD + d) * S_LEN + s] = pk;
      }
    }
  } else {
    float* C = (float*)Cv;
#pragma unroll
    for (int mi = 0; mi < 4; mi++) {
      int r0 = m0 + wr * 64 + mi * 16 + lk * 4;
#pragma unroll
      for (int ni = 0; ni < 4; ni++) {
        int c = n0 + wc * 64 + ni * 16 + lr;
        float bv = bias[c];
#pragma unroll
        for (int r = 0; r < 4; r++)
          C[(r0 + r) * Ndim + c] = acc[mi][ni][r] + bv;
      }
    }
  }
}

// ---------------- flash attention (causal), per-batch ----------------
// grid: (16 q-tiles, 16 heads). 4 waves x 32 q-rows. Q in regs; K [64][128], Vt [128][64] LDS.
__global__ __launch_bounds__(256, 2) void attn_kernel(
    const unsigned short* __restrict__ Q, const unsigned short* __restrict__ K,
    const unsigned short* __restrict__ Vt, unsigned short* __restrict__ ctx) {
  __shared__ unsigned short lds[24576];  // 48 KB
  unsigned short* lK = lds;              // [64][128]
  unsigned short* lV = lds + 8192;       // [128][64]  (V^T)
  unsigned short* lP = lds + 16384;      // [4 waves][32][64]
  unsigned short* lQ = lds;              // [128][128] staging (overlaps lK/lV)

  const int qt = blockIdx.x;
  const int h = blockIdx.y;
  const int t = threadIdx.x, l = t & 63, w = t >> 6;
  const int lr = l & 15, lk = l >> 4;

  const unsigned short* qsrc = Q + (qt * 128) * D_MODEL + h * HD;
#pragma unroll
  for (int i = 0; i < 8; i++)
    gload16(qsrc + (i * 16 + (t >> 4)) * D_MODEL + (t & 15) * 8, lQ + i * 2048 + t * 8);
  __syncthreads();

  short8 Qf[2][4];
#pragma unroll
  for (int mi = 0; mi < 2; mi++)
#pragma unroll
    for (int kk = 0; kk < 4; kk++)
      Qf[mi][kk] = *(const short8*)&lQ[(w * 32 + mi * 16 + lr) * HD + kk * 32 + lk * 8];
  __syncthreads();  // done with lQ before K/V staging reuses it

  f32x4 O[2][8] = {};
  float mrow[2][4], lrow[2][4];
#pragma unroll
  for (int mi = 0; mi < 2; mi++)
#pragma unroll
    for (int r = 0; r < 4; r++) { mrow[mi][r] = -1e30f; lrow[mi][r] = 0.f; }

  const unsigned short* ksrc = K + h * HD;
  const unsigned short* vsrc = Vt + h * HD * S_LEN;
  unsigned short* lPw = lP + w * 2048;
  const int nkv = 2 * qt + 2;
  const float scale = 0.08838834764831845f;  // 1/sqrt(128)

  for (int tk = 0; tk < nkv; tk++) {
    const int kv0 = tk * 64;
#pragma unroll
    for (int i = 0; i < 4; i++)
      gload16(ksrc + (kv0 + i * 16 + (t >> 4)) * D_MODEL + (t & 15) * 8, lK + i * 2048 + t * 8);
#pragma unroll
    for (int i = 0; i < 4; i++)
      gload16(vsrc + (i * 32 + (t >> 3)) * S_LEN + kv0 + (t & 7) * 8, lV + i * 2048 + t * 8);
    __syncthreads();

    // scores S = Q K^T : [32 q rows per wave][64 kv]
    f32x4 sc[2][4] = {};
#pragma unroll
    for (int kk = 0; kk < 4; kk++) {
      short8 Kf[4];
#pragma unroll
      for (int ni = 0; ni < 4; ni++)
        Kf[ni] = *(const short8*)&lK[(ni * 16 + lr) * HD + kk * 32 + lk * 8];
#pragma unroll
      for (int mi = 0; mi < 2; mi++)
#pragma unroll
        for (int ni = 0; ni < 4; ni++)
          sc[mi][ni] = mfma_bf16(Qf[mi][kk], Kf[ni], sc[mi][ni]);
    }

    const bool diag = (tk >= 2 * qt);
#pragma unroll
    for (int mi = 0; mi < 2; mi++) {
      const int qrow0 = qt * 128 + w * 32 + mi * 16 + lk * 4;
#pragma unroll
      for (int ni = 0; ni < 4; ni++) {
        const int col = kv0 + ni * 16 + lr;
#pragma unroll
        for (int r = 0; r < 4; r++) {
          float v = sc[mi][ni][r] * scale;
          if (diag && col > qrow0 + r) v = -1e30f;
          sc[mi][ni][r] = v;
        }
      }
#pragma unroll
      for (int r = 0; r < 4; r++) {
        float rm = fmaxf(fmaxf(sc[mi][0][r], sc[mi][1][r]), fmaxf(sc[mi][2][r], sc[mi][3][r]));
        rm = fmaxf(rm, __shfl_xor(rm, 1));
        rm = fmaxf(rm, __shfl_xor(rm, 2));
        rm = fmaxf(rm, __shfl_xor(rm, 4));
        rm = fmaxf(rm, __shfl_xor(rm, 8));
        const float mo = mrow[mi][r];
        const float mn = fmaxf(mo, rm);
        const float al = __expf(mo - mn);
        float rs = 0.f;
#pragma unroll
        for (int ni = 0; ni < 4; ni++) {
          const float p = __expf(sc[mi][ni][r] - mn);
          sc[mi][ni][r] = p;
          rs += p;
        }
        rs += __shfl_xor(rs, 1);
        rs += __shfl_xor(rs, 2);
        rs += __shfl_xor(rs, 4);
        rs += __shfl_xor(rs, 8);
        mrow[mi][r] = mn;
        lrow[mi][r] = lrow[mi][r] * al + rs;
#pragma unroll
        for (int di = 0; di < 8; di++) O[mi][di][r] *= al;
      }
#pragma unroll
      for (int ni = 0; ni < 4; ni++)
#pragma unroll
        for (int r = 0; r < 4; r++)
          lPw[(mi * 16 + lk * 4 + r) * 64 + ni * 16 + lr] = f2bf(sc[mi][ni][r]);
    }

    // O += P @ V  (V^T layout in LDS)
#pragma unroll
    for (int kk = 0; kk < 2; kk++) {
      short8 Pf[2], Vf[8];
#pragma unroll
      for (int mi = 0; mi < 2; mi++)
        Pf[mi] = *(const short8*)&lPw[(mi * 16 + lr) * 64 + kk * 32 + lk * 8];
#pragma unroll
      for (int di = 0; di < 8; di++)
        Vf[di] = *(const short8*)&lV[(di * 16 + lr) * 64 + kk * 32 + lk * 8];
#pragma unroll
      for (int mi = 0; mi < 2; mi++)
#pragma unroll
        for (int di = 0; di < 8; di++)
          O[mi][di] = mfma_bf16(Pf[mi], Vf[di], O[mi][di]);
    }
    __syncthreads();
  }

#pragma unroll
  for (int mi = 0; mi < 2; mi++) {
    const int row = qt * 128 + w * 32 + mi * 16 + lk * 4;
#pragma unroll
    for (int di = 0; di < 8; di++) {
      const int d = h * HD + di * 16 + lr;
#pragma unroll
      for (int r = 0; r < 4; r++) {
        float v = O[mi][di][r] / lrow[mi][r];
        ctx[(row + r) * D_MODEL + d] = f2bf(v);
      }
    }
  }
}

extern "C" void kernel_launch(void* const* d_in, const int* in_sizes, int n_in,
                              void* d_out, int out_size, void* d_ws, size_t ws_size,
                              hipStream_t stream) {
  const float* x  = (const float*)d_in[0];
  const float* Wq = (const float*)d_in[1];
  const float* Wk = (const float*)d_in[2];
  const float* Wv = (const float*)d_in[3];
  const float* Wo = (const float*)d_in[4];
  const float* bo = (const float*)d_in[5];
  float* out = (float*)d_out;

  // Per-batch workspace, 40 MB peak (ws_size is unknown; 112MB and 72MB layouts
  // both failed post-timing revalidation with corrupted-input signature -> assume
  // ws_size could be as small as ~48MB and stay well under it).
  //   wslot : 4194304 shorts (8 MB)  current transposed weight
  //   xb    : 4194304 shorts (8 MB)  bf16 x for batch b; aliased by ctx after projections
  //   qb    : 4194304 shorts (8 MB)
  //   kb    : 4194304 shorts (8 MB)
  //   vtb   : 4194304 shorts (8 MB)  [H][HD][S]
  unsigned short* ws = (unsigned short*)d_ws;
  unsigned short* wslot = ws;
  unsigned short* xb    = ws + 4194304;
  unsigned short* ctx   = xb;            // alias: attn output overwrites xb
  unsigned short* qb    = ws + 2 * 4194304;
  unsigned short* kb    = ws + 3 * 4194304;
  unsigned short* vtb   = ws + 4 * 4194304;

  dim3 tb(32, 8), tg(64, 64);
  dim3 gg(16, 16);

  for (int b = 0; b < 2; b++) {
    const float* xbatch = x + (size_t)b * S_LEN * D_MODEL;
    float* obatch = out + (size_t)b * S_LEN * D_MODEL;

    cast_bf16<<<4096, 256, 0, stream>>>(xbatch, xb, 1048576);

    transpose_cast<<<tg, tb, 0, stream>>>(Wq, wslot);
    gemm_bt<0><<<gg, 256, 0, stream>>>(xb, wslot, qb, nullptr, S_LEN, D_MODEL, D_MODEL);

    transpose_cast<<<tg, tb, 0, stream>>>(Wk, wslot);
    gemm_bt<0><<<gg, 256, 0, stream>>>(xb, wslot, kb, nullptr, S_LEN, D_MODEL, D_MODEL);

    transpose_cast<<<tg, tb, 0, stream>>>(Wv, wslot);
    gemm_bt<1><<<gg, 256, 0, stream>>>(xb, wslot, vtb, nullptr, S_LEN, D_MODEL, D_MODEL);

    attn_kernel<<<dim3(16, 16), 256, 0, stream>>>(qb, kb, vtb, ctx);

    transpose_cast<<<tg, tb, 0, stream>>>(Wo, wslot);
    gemm_bt<2><<<gg, 256, 0, stream>>>(ctx, wslot, obatch, bo, S_LEN, D_MODEL, D_MODEL);
  }
}

// Round 4
// 545.962 us; speedup vs baseline: 1.2882x; 1.2882x over previous
//
#include <hip/hip_runtime.h>

#define S_LEN 2048
#define D_MODEL 2048
#define NH 16
#define HD 128

typedef __attribute__((ext_vector_type(4))) float f32x4;
typedef __attribute__((ext_vector_type(8))) short short8;
typedef __attribute__((ext_vector_type(8))) __bf16 bf16x8;
typedef __attribute__((ext_vector_type(4))) unsigned short us4;

__device__ __forceinline__ unsigned short f2bf(float f) {
  unsigned int u = __builtin_bit_cast(unsigned int, f);
  return (unsigned short)((u + 0x7fffu + ((u >> 16) & 1u)) >> 16);
}

__device__ __forceinline__ f32x4 mfma_bf16(short8 a, short8 b, f32x4 c) {
  return __builtin_amdgcn_mfma_f32_16x16x32_bf16(
      __builtin_bit_cast(bf16x8, a), __builtin_bit_cast(bf16x8, b), c, 0, 0, 0);
}

__device__ __forceinline__ void gload16(const unsigned short* g, unsigned short* l) {
  __builtin_amdgcn_global_load_lds(
      (const __attribute__((address_space(1))) void*)g,
      (__attribute__((address_space(3))) void*)l, 16, 0, 0);
}

// ---------------- cast x (f32 -> bf16) ----------------
__global__ void cast_bf16(const float* __restrict__ src, unsigned short* __restrict__ dst, int n4) {
  int i = blockIdx.x * blockDim.x + threadIdx.x;
  if (i < n4) {
    float4 v = ((const float4*)src)[i];
    us4 o = { f2bf(v.x), f2bf(v.y), f2bf(v.z), f2bf(v.w) };
    ((us4*)dst)[i] = o;
  }
}

// ---------------- transpose-cast weights: W[k][n] f32 -> Wt[n][k] bf16 ----------------
__global__ void transpose_cast(const float* __restrict__ W, unsigned short* __restrict__ Wt) {
  __shared__ unsigned short tile[32][33];
  int bx = blockIdx.x * 32, by = blockIdx.y * 32;
  int tx = threadIdx.x, ty = threadIdx.y;
#pragma unroll
  for (int i = 0; i < 32; i += 8)
    tile[ty + i][tx] = f2bf(W[(by + ty + i) * D_MODEL + bx + tx]);
  __syncthreads();
#pragma unroll
  for (int i = 0; i < 32; i += 8)
    Wt[(bx + ty + i) * D_MODEL + by + tx] = tile[tx][ty + i];
}

// ---------------- GEMM: C[M,N] = A[M,K] @ Bt[N,K]^T, bf16 in, 128x128 tile ----------------
// MODE 0: bf16 row-major out. MODE 1: v-layout out [H][HD][S] (per-batch, M==S_LEN).
// MODE 2: f32 + bias out.
template <int MODE>
__global__ __launch_bounds__(256, 2) void gemm_bt(
    const unsigned short* __restrict__ A, const unsigned short* __restrict__ Bt,
    void* __restrict__ Cv, const float* __restrict__ bias, int Mdim, int Ndim, int Kdim) {
  __shared__ unsigned short lA[128 * 32];
  __shared__ unsigned short lB[128 * 32];
  const int t = threadIdx.x;
  const int l = t & 63, w = t >> 6;
  const int wr = w >> 1, wc = w & 1;
  const int lr = l & 15, lk = l >> 4;
  const int m0 = blockIdx.y * 128, n0 = blockIdx.x * 128;

  const int arow = t >> 2, acol = (t & 3) * 8;
  const unsigned short* Ag0 = A + (m0 + arow) * Kdim + acol;
  const unsigned short* Ag1 = Ag0 + 64 * Kdim;
  const unsigned short* Bg0 = Bt + (n0 + arow) * Kdim + acol;
  const unsigned short* Bg1 = Bg0 + 64 * Kdim;
  unsigned short* la = lA + t * 8;
  unsigned short* lb = lB + t * 8;

  f32x4 acc[4][4] = {};

  for (int kt = 0; kt < Kdim; kt += 32) {
    gload16(Ag0 + kt, la);
    gload16(Ag1 + kt, la + 2048);
    gload16(Bg0 + kt, lb);
    gload16(Bg1 + kt, lb + 2048);
    __syncthreads();
    short8 af[4], bf[4];
#pragma unroll
    for (int mi = 0; mi < 4; mi++)
      af[mi] = *(const short8*)&lA[(wr * 64 + mi * 16 + lr) * 32 + lk * 8];
#pragma unroll
    for (int ni = 0; ni < 4; ni++)
      bf[ni] = *(const short8*)&lB[(wc * 64 + ni * 16 + lr) * 32 + lk * 8];
#pragma unroll
    for (int mi = 0; mi < 4; mi++)
#pragma unroll
      for (int ni = 0; ni < 4; ni++)
        acc[mi][ni] = mfma_bf16(af[mi], bf[ni], acc[mi][ni]);
    __syncthreads();
  }

  if (MODE == 0) {
    unsigned short* C = (unsigned short*)Cv;
#pragma unroll
    for (int mi = 0; mi < 4; mi++) {
      int r0 = m0 + wr * 64 + mi * 16 + lk * 4;
#pragma unroll
      for (int ni = 0; ni < 4; ni++) {
        int c = n0 + wc * 64 + ni * 16 + lr;
#pragma unroll
        for (int r = 0; r < 4; r++)
          C[(r0 + r) * Ndim + c] = f2bf(acc[mi][ni][r]);
      }
    }
  } else if (MODE == 1) {
#pragma unroll
    for (int mi = 0; mi < 4; mi++) {
      int s = m0 + wr * 64 + mi * 16 + lk * 4;  // sequence position (4 consecutive)
#pragma unroll
      for (int ni = 0; ni < 4; ni++) {
        int n = n0 + wc * 64 + ni * 16 + lr;
        int h = n >> 7, d = n & (HD - 1);
        us4 pk = { f2bf(acc[mi][ni][0]), f2bf(acc[mi][ni][1]),
                   f2bf(acc[mi][ni][2]), f2bf(acc[mi][ni][3]) };
        *(us4*)&((unsigned short*)Cv)[(h * HD + d) * S_LEN + s] = pk;
      }
    }
  } else {
    float* C = (float*)Cv;
#pragma unroll
    for (int mi = 0; mi < 4; mi++) {
      int r0 = m0 + wr * 64 + mi * 16 + lk * 4;
#pragma unroll
      for (int ni = 0; ni < 4; ni++) {
        int c = n0 + wc * 64 + ni * 16 + lr;
        float bv = bias[c];
#pragma unroll
        for (int r = 0; r < 4; r++)
          C[(r0 + r) * Ndim + c] = acc[mi][ni][r] + bv;
      }
    }
  }
}

// ---------------- flash attention (causal), per-batch ----------------
// grid: 512 blocks (32 q-tiles of 64 rows x 16 heads), 4 waves x 16 q-rows.
// Q in registers. K double-buffered LDS [64][128], V single-buffered [128][64] (V^T),
// all XOR-swizzled (pre-swizzled global source for global_load_lds, swizzled ds_read).
// Counted vmcnt (never 0 mid-loop) + raw s_barrier: K(t+1) and V(t) stay in flight
// under compute.
__global__ __launch_bounds__(256, 2) void attn_kernel(
    const unsigned short* __restrict__ Q, const unsigned short* __restrict__ K,
    const unsigned short* __restrict__ Vt, unsigned short* __restrict__ ctx) {
  __shared__ unsigned short lds[28672];  // 56 KB
  unsigned short* lK0 = lds;             // [64][128] K buf 0
  unsigned short* lK1 = lds + 8192;      // [64][128] K buf 1
  unsigned short* lV  = lds + 16384;     // [128][64] V^T
  unsigned short* lP  = lds + 24576;     // [4 waves][16][64]

  const int id = blockIdx.x;
  const int h = id & 15;
  const int qtl = id >> 4;
  // causal load-balance: pair tiles so blocks id and id+256 (same CU under
  // XCD round-robin) get qt summing to 31.
  const int qt = (qtl < 16) ? (2 * qtl) : (63 - 2 * qtl);

  const int t = threadIdx.x, l = t & 63, w = t >> 6;
  const int lr = l & 15, lk = l >> 4;

  // Q fragment direct from global: rows qt*64 + w*16 + lr, k-chunks kk*32+lk*8
  const unsigned short* qsrc = Q + (size_t)(qt * 64 + w * 16 + lr) * D_MODEL + h * HD;
  short8 Qf[4];
#pragma unroll
  for (int kk = 0; kk < 4; kk++)
    Qf[kk] = *(const short8*)&qsrc[kk * 32 + lk * 8];

  const unsigned short* ksrc = K + h * HD;
  const unsigned short* vsrc = Vt + (size_t)h * HD * S_LEN;

  const int krow = t >> 4;  // + i*16  (K stage row)
  const int kcs  = t & 15;  // K stage phys 16B-unit
  const int vrow = t >> 3;  // + i*32  (V stage row)
  const int vcs  = t & 7;   // V stage phys 16B-unit

  f32x4 O[8] = {};
  float mrow[4] = {-1e30f, -1e30f, -1e30f, -1e30f};
  float lrow[4] = {0.f, 0.f, 0.f, 0.f};

  const int nkv = qt + 1;
  const float scale = 0.08838834764831845f;  // 1/sqrt(128)

  // prologue: stage K tile 0 into lK0 (source pre-swizzled: unit ^= row&7)
#pragma unroll
  for (int i = 0; i < 4; i++) {
    int row = i * 16 + krow;
    gload16(ksrc + (size_t)row * D_MODEL + ((kcs ^ (row & 7)) * 8),
            lK0 + row * 128 + kcs * 8);
  }

  for (int tk = 0; tk < nkv; tk++) {
    const int kv0 = tk * 64;
    unsigned short* lKc = (tk & 1) ? lK1 : lK0;
    unsigned short* lKn = (tk & 1) ? lK0 : lK1;
    const bool more = (tk + 1 < nkv);

    // stage V(tk) (swizzled source)
#pragma unroll
    for (int i = 0; i < 4; i++) {
      int row = i * 32 + vrow;
      gload16(vsrc + (size_t)row * S_LEN + kv0 + ((vcs ^ (row & 7)) * 8),
              lV + row * 64 + vcs * 8);
    }
    if (more) {
      // stage K(tk+1) into the other K buffer
#pragma unroll
      for (int i = 0; i < 4; i++) {
        int row = i * 16 + krow;
        gload16(ksrc + (size_t)(kv0 + 64 + row) * D_MODEL + ((kcs ^ (row & 7)) * 8),
                lKn + row * 128 + kcs * 8);
      }
      asm volatile("s_waitcnt vmcnt(8)" ::: "memory");  // K(tk) done; V(tk),K(tk+1) in flight
    } else {
      asm volatile("s_waitcnt vmcnt(4)" ::: "memory");  // K(tk) done; V(tk) in flight
    }
    __builtin_amdgcn_sched_barrier(0);
    __builtin_amdgcn_s_barrier();
    __builtin_amdgcn_sched_barrier(0);

    // ---- QK^T: [16 q rows per wave][64 kv] ----
    f32x4 sc[4] = {};
    __builtin_amdgcn_s_setprio(1);
#pragma unroll
    for (int kk = 0; kk < 4; kk++) {
      short8 Kf[4];
#pragma unroll
      for (int ni = 0; ni < 4; ni++)
        Kf[ni] = *(const short8*)&lKc[(ni * 16 + lr) * 128 + (((kk * 4 + lk) ^ (lr & 7)) * 8)];
#pragma unroll
      for (int ni = 0; ni < 4; ni++)
        sc[ni] = mfma_bf16(Qf[kk], Kf[ni], sc[ni]);
    }
    __builtin_amdgcn_s_setprio(0);

    // ---- softmax (online) ----
    const bool diag = (tk == qt);
    const int row0 = qt * 64 + w * 16 + lk * 4;
#pragma unroll
    for (int ni = 0; ni < 4; ni++) {
      const int col = kv0 + ni * 16 + lr;
#pragma unroll
      for (int r = 0; r < 4; r++) {
        float v = sc[ni][r] * scale;
        if (diag && col > row0 + r) v = -1e30f;
        sc[ni][r] = v;
      }
    }
#pragma unroll
    for (int r = 0; r < 4; r++) {
      float rm = fmaxf(fmaxf(sc[0][r], sc[1][r]), fmaxf(sc[2][r], sc[3][r]));
      rm = fmaxf(rm, __shfl_xor(rm, 1));
      rm = fmaxf(rm, __shfl_xor(rm, 2));
      rm = fmaxf(rm, __shfl_xor(rm, 4));
      rm = fmaxf(rm, __shfl_xor(rm, 8));
      const float mo = mrow[r];
      const float mn = fmaxf(mo, rm);
      const float al = __expf(mo - mn);
      float rs = 0.f;
#pragma unroll
      for (int ni = 0; ni < 4; ni++) {
        const float p = __expf(sc[ni][r] - mn);
        sc[ni][r] = p;
        rs += p;
      }
      rs += __shfl_xor(rs, 1);
      rs += __shfl_xor(rs, 2);
      rs += __shfl_xor(rs, 4);
      rs += __shfl_xor(rs, 8);
      mrow[r] = mn;
      lrow[r] = lrow[r] * al + rs;
#pragma unroll
      for (int di = 0; di < 8; di++) O[di][r] *= al;
    }

    // ---- write P to LDS (swizzled: unit ^= row&7) ----
    unsigned short* lPw = lP + w * 1024;
#pragma unroll
    for (int ni = 0; ni < 4; ni++)
#pragma unroll
      for (int r = 0; r < 4; r++) {
        int prow = lk * 4 + r;
        int pu = (ni * 2 + (lr >> 3)) ^ (prow & 7);
        lPw[prow * 64 + pu * 8 + (lr & 7)] = f2bf(sc[ni][r]);
      }

    // ---- wait V(tk), sync, then PV ----
    if (more) {
      asm volatile("s_waitcnt vmcnt(4)" ::: "memory");  // V(tk) done; K(tk+1) in flight
    } else {
      asm volatile("s_waitcnt vmcnt(0)" ::: "memory");
    }
    __builtin_amdgcn_sched_barrier(0);
    __builtin_amdgcn_s_barrier();
    __builtin_amdgcn_sched_barrier(0);

    __builtin_amdgcn_s_setprio(1);
#pragma unroll
    for (int kk = 0; kk < 2; kk++) {
      short8 Pf = *(const short8*)&lPw[lr * 64 + (((kk * 4 + lk) ^ (lr & 7)) * 8)];
#pragma unroll
      for (int di = 0; di < 8; di++) {
        short8 Vf = *(const short8*)&lV[(di * 16 + lr) * 64 + (((kk * 4 + lk) ^ (lr & 7)) * 8)];
        O[di] = mfma_bf16(Pf, Vf, O[di]);
      }
    }
    __builtin_amdgcn_s_setprio(0);

    __builtin_amdgcn_s_barrier();  // V / P / K[cur] reusable next iteration
    __builtin_amdgcn_sched_barrier(0);
  }

  // epilogue
#pragma unroll
  for (int di = 0; di < 8; di++) {
#pragma unroll
    for (int r = 0; r < 4; r++) {
      float v = O[di][r] / lrow[r];
      ctx[(size_t)(qt * 64 + w * 16 + lk * 4 + r) * D_MODEL + h * HD + di * 16 + lr] = f2bf(v);
    }
  }
}

extern "C" void kernel_launch(void* const* d_in, const int* in_sizes, int n_in,
                              void* d_out, int out_size, void* d_ws, size_t ws_size,
                              hipStream_t stream) {
  const float* x  = (const float*)d_in[0];
  const float* Wq = (const float*)d_in[1];
  const float* Wk = (const float*)d_in[2];
  const float* Wv = (const float*)d_in[3];
  const float* Wo = (const float*)d_in[4];
  const float* bo = (const float*)d_in[5];
  float* out = (float*)d_out;

  // Per-batch workspace, 40 MB peak (ws_size unknown; 72MB failed, 40MB passes).
  unsigned short* ws = (unsigned short*)d_ws;
  unsigned short* wslot = ws;
  unsigned short* xb    = ws + 4194304;
  unsigned short* ctx   = xb;            // alias: attn output overwrites xb
  unsigned short* qb    = ws + 2 * 4194304;
  unsigned short* kb    = ws + 3 * 4194304;
  unsigned short* vtb   = ws + 4 * 4194304;

  dim3 tb(32, 8), tg(64, 64);
  dim3 gg(16, 16);

  for (int b = 0; b < 2; b++) {
    const float* xbatch = x + (size_t)b * S_LEN * D_MODEL;
    float* obatch = out + (size_t)b * S_LEN * D_MODEL;

    cast_bf16<<<4096, 256, 0, stream>>>(xbatch, xb, 1048576);

    transpose_cast<<<tg, tb, 0, stream>>>(Wq, wslot);
    gemm_bt<0><<<gg, 256, 0, stream>>>(xb, wslot, qb, nullptr, S_LEN, D_MODEL, D_MODEL);

    transpose_cast<<<tg, tb, 0, stream>>>(Wk, wslot);
    gemm_bt<0><<<gg, 256, 0, stream>>>(xb, wslot, kb, nullptr, S_LEN, D_MODEL, D_MODEL);

    transpose_cast<<<tg, tb, 0, stream>>>(Wv, wslot);
    gemm_bt<1><<<gg, 256, 0, stream>>>(xb, wslot, vtb, nullptr, S_LEN, D_MODEL, D_MODEL);

    attn_kernel<<<dim3(512), 256, 0, stream>>>(qb, kb, vtb, ctx);

    transpose_cast<<<tg, tb, 0, stream>>>(Wo, wslot);
    gemm_bt<2><<<gg, 256, 0, stream>>>(ctx, wslot, obatch, bo, S_LEN, D_MODEL, D_MODEL);
  }
}